// Round 4
// baseline (36.043 us; speedup 1.0000x reference)
//
#include <hip/hip_runtime.h>
#include <math.h>

#define B 16
#define N 1024
#define D 512
#define K 32
#define EPSF 1e-12f

// ws float offsets
#define WS_WT_F   0        // WT bf16 [32][512] = 16384 u16 = 8192 f
#define WS_CT_F   8192     // CT f32 [32][512] = 16384 f
#define WS_ASP_F  24576    // assign partials [1024][32] f32
#define WS_ENTP_F 57344    // [1024]
#define WS_MSKP_F 58368    // [1024]
#define WS_PART_F 59392    // parts bf16 [32][16][32][512] = 8388608 u16

#define OFF_DIST 262144
#define OFF_ENT  262656

typedef __attribute__((ext_vector_type(8))) short s16x8;
typedef __attribute__((ext_vector_type(4))) short s16x4;
typedef __attribute__((ext_vector_type(4))) float f32x4;

__device__ __forceinline__ ushort f2b(float f) {
    unsigned u = __builtin_bit_cast(unsigned, f);
    u += 0x7fffu + ((u >> 16) & 1u);   // RTNE
    return (ushort)(u >> 16);
}
__device__ __forceinline__ float b2f(ushort u) {
    return __builtin_bit_cast(float, (unsigned)u << 16);
}

// k0: block 0: W[d][k] f32 -> WT[k][d] bf16 ; block 1: cent[d][k] -> CT[k][d] f32
__global__ __launch_bounds__(256) void k0_prep(const float* __restrict__ Wf,
    const float* __restrict__ cent, float* __restrict__ ws)
{
    const int t = threadIdx.x;
    const int kk = t >> 3, dseg = (t & 7) * 64;
    if (blockIdx.x == 0) {
        ushort* wt = (ushort*)(ws + WS_WT_F);
        #pragma unroll
        for (int d8 = 0; d8 < 8; ++d8) {
            s16x8 v;
            #pragma unroll
            for (int e = 0; e < 8; ++e)
                v[e] = f2b(Wf[(dseg + d8 * 8 + e) * 32 + kk]);
            *(s16x8*)(wt + kk * 512 + dseg + d8 * 8) = v;
        }
    } else {
        float* ct = ws + WS_CT_F;
        #pragma unroll
        for (int d4 = 0; d4 < 16; ++d4) {
            float4 v;
            v.x = cent[(dseg + d4 * 4 + 0) * 32 + kk];
            v.y = cent[(dseg + d4 * 4 + 1) * 32 + kk];
            v.z = cent[(dseg + d4 * 4 + 2) * 32 + kk];
            v.w = cent[(dseg + d4 * 4 + 3) * 32 + kk];
            *(float4*)(ct + kk * 512 + dseg + d4 * 4) = v;
        }
    }
}

// kA: 512 blocks (b, s32) x 256 thr (4 waves: rw = row-half, dw = d-half).
// Phase 1: logits via MFMA (A-frags = WT from global), fused masked softmax.
// Phase 2: in-block VLAD outer product via MFMA (t^T, x^T from LDS),
//          bf16 partials to parts[s][b][k][d] with coalesced 16B stores.
__global__ __launch_bounds__(256, 2) void kA(const float* __restrict__ x,
    const float* __restrict__ mask, const float* __restrict__ bias,
    float* __restrict__ ws, ushort* __restrict__ parts)
{
    __shared__ ushort xs[4 * 2048];     // 16KB per-wave QK x tiles (swizzled)
    __shared__ ushort xsT[512 * 36];    // 36KB x^T [d][n+pad]; reused as stg
    __shared__ ushort tls[32 * 32];     // 2KB t^T [k][n]
    __shared__ float4 accsh[2 * 128];   // 4KB
    __shared__ float ssqsh[32], invsh[32];

    const int bid = blockIdx.x;
    const int b = bid >> 5;
    const int s = bid & 31;
    const int tid = threadIdx.x;
    const int w = tid >> 6;
    const int rw = w & 1, dw = w >> 1;
    const int l = tid & 63;
    const int g = l >> 4, lo = l & 15;
    const int n0 = s * 32 + rw * 16;
    const int p = bid * 2 + rw;
    const ushort* wt = (const ushort*)(ws + WS_WT_F);

    ushort* xw = xs + w * 2048;
    float ssq[8] = {0.f, 0.f, 0.f, 0.f, 0.f, 0.f, 0.f, 0.f};
    f32x4 acc[2] = {{0.f, 0.f, 0.f, 0.f}, {0.f, 0.f, 0.f, 0.f}};
    const float4* xg = (const float4*)(x + (size_t)(b * N + n0) * D);

    #pragma unroll
    for (int cc = 0; cc < 2; ++cc) {
        const int c = dw * 2 + cc;
        float4 fv[8];
        #pragma unroll
        for (int j = 0; j < 8; ++j) {
            int idx = l + 64 * j;
            fv[j] = xg[(idx >> 5) * 128 + c * 32 + (idx & 31)];
        }
        #pragma unroll
        for (int j = 0; j < 8; ++j)
            ssq[j] += fv[j].x * fv[j].x + fv[j].y * fv[j].y
                    + fv[j].z * fv[j].z + fv[j].w * fv[j].w;
        #pragma unroll
        for (int j = 0; j < 8; ++j) {
            int idx = l + 64 * j;
            int r = idx >> 5, c4 = idx & 31;
            unsigned bo = (unsigned)(c4 * 8) ^ (unsigned)((r & 7) << 4);
            s16x4 sv = { (short)f2b(fv[j].x), (short)f2b(fv[j].y),
                         (short)f2b(fv[j].z), (short)f2b(fv[j].w) };
            *(s16x4*)&xw[r * 128 + (bo >> 1)] = sv;
            // x^T LDS tile for the VLAD phase: xsT[d][n], row stride 36 u16
            int nn = rw * 16 + r;
            int dbase = c * 128 + c4 * 4;
            xsT[(dbase + 0) * 36 + nn] = (ushort)sv[0];
            xsT[(dbase + 1) * 36 + nn] = (ushort)sv[1];
            xsT[(dbase + 2) * 36 + nn] = (ushort)sv[2];
            xsT[(dbase + 3) * 36 + nn] = (ushort)sv[3];
        }
        #pragma unroll
        for (int ks = 0; ks < 4; ++ks) {
            unsigned bo = (unsigned)(ks * 64 + g * 16) ^ (unsigned)((lo & 7) << 4);
            s16x8 bfrag = *(const s16x8*)&xw[lo * 128 + (bo >> 1)];
            int dglob = c * 128 + ks * 32 + g * 8;
            s16x8 a0 = *(const s16x8*)(wt + (size_t)lo * 512 + dglob);
            s16x8 a1 = *(const s16x8*)(wt + (size_t)(16 + lo) * 512 + dglob);
            acc[0] = __builtin_amdgcn_mfma_f32_16x16x32_bf16(a0, bfrag, acc[0], 0, 0, 0);
            acc[1] = __builtin_amdgcn_mfma_f32_16x16x32_bf16(a1, bfrag, acc[1], 0, 0, 0);
        }
    }

    // per-row sumsq butterfly (rows (l>>5)+2j over 32-lane groups)
    #pragma unroll
    for (int j = 0; j < 8; ++j) {
        #pragma unroll
        for (int m = 16; m; m >>= 1) ssq[j] += __shfl_xor(ssq[j], m);
    }
    if (dw == 1) {
        if ((l & 31) == 0) {
            #pragma unroll
            for (int j = 0; j < 8; ++j)
                ssqsh[rw * 16 + (l >> 5) + 2 * j] = ssq[j];
        }
        accsh[rw * 128 + l * 2 + 0] = *(float4*)&acc[0];
        accsh[rw * 128 + l * 2 + 1] = *(float4*)&acc[1];
    }
    __syncthreads();
    if (dw == 0) {
        float4 o0 = accsh[rw * 128 + l * 2 + 0];
        float4 o1 = accsh[rw * 128 + l * 2 + 1];
        acc[0][0] += o0.x; acc[0][1] += o0.y; acc[0][2] += o0.z; acc[0][3] += o0.w;
        acc[1][0] += o1.x; acc[1][1] += o1.y; acc[1][2] += o1.z; acc[1][3] += o1.w;
        if ((l & 31) == 0) {
            #pragma unroll
            for (int j = 0; j < 8; ++j) {
                int r = (l >> 5) + 2 * j;
                invsh[rw * 16 + r] = 1.f / fmaxf(sqrtf(ssq[j] + ssqsh[rw * 16 + r]), EPSF);
            }
        }
    }
    __syncthreads();
    if (dw == 0) {
        const float inv = invsh[rw * 16 + lo];
        const float mv = mask[b * N + n0 + lo];
        float lg[2][4];
        #pragma unroll
        for (int kt = 0; kt < 2; ++kt)
            #pragma unroll
            for (int r = 0; r < 4; ++r)
                lg[kt][r] = (acc[kt][r] * inv + bias[kt * 16 + g * 4 + r]) * mv;
        float mx = lg[0][0];
        #pragma unroll
        for (int kt = 0; kt < 2; ++kt)
            #pragma unroll
            for (int r = 0; r < 4; ++r) mx = fmaxf(mx, lg[kt][r]);
        mx = fmaxf(mx, __shfl_xor(mx, 16));
        mx = fmaxf(mx, __shfl_xor(mx, 32));
        float e[2][4], sum = 0.f;
        #pragma unroll
        for (int kt = 0; kt < 2; ++kt)
            #pragma unroll
            for (int r = 0; r < 4; ++r) { e[kt][r] = __expf(lg[kt][r] - mx); sum += e[kt][r]; }
        sum += __shfl_xor(sum, 16);
        sum += __shfl_xor(sum, 32);
        const float rs = mv / sum;
        float sa[2][4], ent = 0.f;
        #pragma unroll
        for (int kt = 0; kt < 2; ++kt)
            #pragma unroll
            for (int r = 0; r < 4; ++r) {
                sa[kt][r] = e[kt][r] * rs;
                ent += sa[kt][r] > 0.f ? -sa[kt][r] * __log2f(sa[kt][r]) : 0.f;
            }
        #pragma unroll
        for (int m = 32; m; m >>= 1) ent += __shfl_xor(ent, m);
        if (l == 0) ws[WS_ENTP_F + p] = ent;
        float mp = mv;
        #pragma unroll
        for (int m = 8; m; m >>= 1) mp += __shfl_xor(mp, m);
        if (l == 0) ws[WS_MSKP_F + p] = mp;
        #pragma unroll
        for (int kt = 0; kt < 2; ++kt)
            #pragma unroll
            for (int r = 0; r < 4; ++r) {
                float av = sa[kt][r];
                #pragma unroll
                for (int m = 8; m; m >>= 1) av += __shfl_xor(av, m);
                if (lo == 0) ws[WS_ASP_F + p * 32 + kt * 16 + g * 4 + r] = av;
            }
        // t^T -> tls[k][n-in-block]
        #pragma unroll
        for (int kt = 0; kt < 2; ++kt)
            #pragma unroll
            for (int r = 0; r < 4; ++r)
                tls[(kt * 16 + g * 4 + r) * 32 + rw * 16 + lo] = f2b(sa[kt][r] * inv);
    }
    __syncthreads();   // tls ready (xsT written pre-sync#1)

    // VLAD phase: wave w owns d-quarter [w*128, w*128+128)
    f32x4 acc2[2][8];
    #pragma unroll
    for (int kt = 0; kt < 2; ++kt)
        #pragma unroll
        for (int dt = 0; dt < 8; ++dt)
            acc2[kt][dt] = (f32x4){0.f, 0.f, 0.f, 0.f};
    {
        s16x8 av0 = *(const s16x8*)&tls[lo * 32 + g * 8];
        s16x8 av1 = *(const s16x8*)&tls[(16 + lo) * 32 + g * 8];
        #pragma unroll
        for (int dt = 0; dt < 8; ++dt) {
            int d = w * 128 + dt * 16 + lo;
            s16x4 b0 = *(const s16x4*)&xsT[d * 36 + g * 8];
            s16x4 b1 = *(const s16x4*)&xsT[d * 36 + g * 8 + 4];
            s16x8 bv;
            bv[0] = b0[0]; bv[1] = b0[1]; bv[2] = b0[2]; bv[3] = b0[3];
            bv[4] = b1[0]; bv[5] = b1[1]; bv[6] = b1[2]; bv[7] = b1[3];
            acc2[0][dt] = __builtin_amdgcn_mfma_f32_16x16x32_bf16(av0, bv, acc2[0][dt], 0, 0, 0);
            acc2[1][dt] = __builtin_amdgcn_mfma_f32_16x16x32_bf16(av1, bv, acc2[1][dt], 0, 0, 0);
        }
    }
    __syncthreads();   // all xsT reads done; reuse as staging [32k][520]
    ushort* stg = xsT;
    #pragma unroll
    for (int kt = 0; kt < 2; ++kt)
        #pragma unroll
        for (int dt = 0; dt < 8; ++dt)
            #pragma unroll
            for (int r = 0; r < 4; ++r)
                stg[(kt * 16 + g * 4 + r) * 520 + w * 128 + dt * 16 + lo] = f2b(acc2[kt][dt][r]);
    __syncthreads();
    #pragma unroll
    for (int j = 0; j < 8; ++j) {
        int k = w * 8 + j;
        s16x8 v = *(const s16x8*)&stg[k * 520 + l * 8];
        *(s16x8*)(parts + ((size_t)(s * 16 + b) * 32 + k) * 512 + l * 8) = v;
    }
}

// kC: 512 blocks (b, k) x 128 thr: assign_sum, dist (k==0), entropy (bid 0),
// vlad = sum_s parts - CT*as, intra-D normalize, write out (B,K,D).
__global__ __launch_bounds__(128) void kC(const float* __restrict__ ws,
    const ushort* __restrict__ parts, float* __restrict__ out)
{
    __shared__ float pm[128];
    __shared__ float asL[32];
    __shared__ float red[2];
    const int bid = blockIdx.x;
    const int b = bid >> 5, k = bid & 31;
    const int t = threadIdx.x;
    {
        int kk = t & 31, i = t >> 5;       // i in 0..3
        float a = 0.f;
        #pragma unroll
        for (int ii = 0; ii < 16; ++ii)
            a += ws[WS_ASP_F + (size_t)(b * 64 + ii * 4 + i) * 32 + kk];
        pm[t] = a;
    }
    __syncthreads();
    if (t < 32) {
        float a = 0.f;
        #pragma unroll
        for (int i = 0; i < 4; ++i) a += pm[i * 32 + t];
        asL[t] = a;
    }
    __syncthreads();
    if (k == 0 && t < 32) {
        float a = asL[t];
        float mx = a;
        #pragma unroll
        for (int m = 16; m; m >>= 1) mx = fmaxf(mx, __shfl_xor(mx, m));
        float e = __expf(a - mx), ssum = e;
        #pragma unroll
        for (int m = 16; m; m >>= 1) ssum += __shfl_xor(ssum, m);
        out[OFF_DIST + b * 32 + t] = a - mx - logf(ssum);
    }
    if (bid == 0 && (t >> 6) == 1) {
        int l = t & 63;
        float es = 0.f, ms = 0.f;
        for (int i = l; i < 1024; i += 64) {
            es += ws[WS_ENTP_F + i];
            ms += ws[WS_MSKP_F + i];
        }
        #pragma unroll
        for (int m = 32; m; m >>= 1) { es += __shfl_xor(es, m); ms += __shfl_xor(ms, m); }
        if (l == 0) out[OFF_ENT] = es / ms;
    }
    const int d0 = t * 4;
    float a0 = 0.f, a1 = 0.f, a2 = 0.f, a3 = 0.f;
    for (int s = 0; s < 32; ++s) {
        s16x4 v = *(const s16x4*)(parts + ((size_t)(s * 16 + b) * 32 + k) * 512 + d0);
        a0 += b2f((ushort)v[0]);
        a1 += b2f((ushort)v[1]);
        a2 += b2f((ushort)v[2]);
        a3 += b2f((ushort)v[3]);
    }
    const float as = asL[k];
    float4 ct = *(const float4*)(ws + WS_CT_F + k * 512 + d0);
    float v0 = a0 - ct.x * as;
    float v1 = a1 - ct.y * as;
    float v2 = a2 - ct.z * as;
    float v3 = a3 - ct.w * as;
    float sq = v0 * v0 + v1 * v1 + v2 * v2 + v3 * v3;
    #pragma unroll
    for (int m = 32; m; m >>= 1) sq += __shfl_xor(sq, m);
    if ((t & 63) == 0) red[t >> 6] = sq;
    __syncthreads();
    float sc = 1.f / fmaxf(sqrtf(red[0] + red[1]), EPSF);
    float4 o = make_float4(v0 * sc, v1 * sc, v2 * sc, v3 * sc);
    *(float4*)(out + (size_t)(b * 32 + k) * 512 + d0) = o;
}

extern "C" void kernel_launch(void* const* d_in, const int* in_sizes, int n_in,
                              void* d_out, int out_size, void* d_ws, size_t ws_size,
                              hipStream_t stream)
{
    const float* x    = (const float*)d_in[0];
    const float* mask = (const float*)d_in[1];
    const float* W    = (const float*)d_in[2];
    const float* bias = (const float*)d_in[3];
    const float* cent = (const float*)d_in[4];
    float* out = (float*)d_out;
    float* ws  = (float*)d_ws;
    ushort* parts = (ushort*)(ws + WS_PART_F);

    k0_prep<<<dim3(2), dim3(256), 0, stream>>>(W, cent, ws);
    kA<<<dim3(512), dim3(256), 0, stream>>>(x, mask, bias, ws, parts);
    kC<<<dim3(512), dim3(128), 0, stream>>>(ws, parts, out);
}